// Round 1
// baseline (510.492 us; speedup 1.0000x reference)
//
#include <hip/hip_runtime.h>

namespace {

constexpr float kAlpha = 0.025f;
constexpr float kC1 = 1.0e-4f;  // (0.01*1)^2
constexpr float kC2 = 9.0e-4f;  // (0.03*1)^2

// LDS: 32 KB patches + 40 KB H-buffers + taps + reduce = 74.4 KB -> 2 blocks/CU
struct Smem {
  float sx[64 * 64];      // x patch (32x32 tile + 16 halo each side)
  float sy[64 * 64];      // y patch
  float hb[5][64 * 32];   // horizontal-conv buffers, row-major [row][col]
  float g1[5 * 33];       // 1D taps per sigma
  float red[4];           // per-wave partials
};

// One sigma: horizontal pass (all 256 threads, 4-col register windows),
// vertical pass (128 threads, 8-row register strips, col-per-thread),
// then per-pixel cs/luminance combine. R = truncated radius.
template <int R, bool LAST>
__device__ __forceinline__ void process_sigma(Smem& sm, int s, int tid,
                                              float Pcs[8], float lumP[8],
                                              float l1v[8]) {
  constexpr int T = 2 * R + 1;
  float g[T];
  const float* gb = sm.g1 + s * 33 + (16 - R);
#pragma unroll
  for (int j = 0; j < T; ++j) g[j] = gb[j];

  __syncthreads();  // previous sigma's vertical reads of hb are done

  // ---- horizontal: H rows [16-R, 48+R), 32 cols, 5 maps ----
  constexpr int ROWS = 32 + 2 * R;
  constexpr int LO = (16 - R) & ~3;                  // aligned window start
  constexpr int NF = ((16 + R + 3 - LO) / 4 + 1) * 4;  // window floats
  for (int idx = tid; idx < ROWS * 8; idx += 256) {
    int pr = (16 - R) + (idx >> 3);
    int c0 = (idx & 7) << 2;
    float wx[NF], wy[NF];
    const float4* px = (const float4*)(sm.sx + pr * 64 + c0 + LO);
    const float4* py = (const float4*)(sm.sy + pr * 64 + c0 + LO);
#pragma unroll
    for (int q = 0; q < NF / 4; ++q) {
      *(float4*)(wx + 4 * q) = px[q];
      *(float4*)(wy + 4 * q) = py[q];
    }
#pragma unroll
    for (int o = 0; o < 4; ++o) {
      float ax = 0.f, ay = 0.f, axx = 0.f, ayy = 0.f, axy = 0.f;
#pragma unroll
      for (int j = 0; j < T; ++j) {
        int wi = 16 + o + (j - R) - LO;
        float vx = wx[wi], vy = wy[wi];
        float gt = g[j];
        float tx = gt * vx, ty = gt * vy;
        ax += tx;
        ay += ty;
        axx = fmaf(tx, vx, axx);
        ayy = fmaf(ty, vy, ayy);
        axy = fmaf(tx, vy, axy);
      }
      int off = pr * 32 + c0 + o;
      sm.hb[0][off] = ax;
      sm.hb[1][off] = ay;
      sm.hb[2][off] = axx;
      sm.hb[3][off] = ayy;
      sm.hb[4][off] = axy;
    }
  }
  __syncthreads();

  // ---- vertical + combine: thread t<128 owns column (t&31), rows r0..r0+7 ----
  if (tid < 128) {
    int c = tid & 31;
    int r0 = (tid >> 5) << 3;
    float acc[5][8];
#pragma unroll
    for (int m = 0; m < 5; ++m)
#pragma unroll
      for (int k = 0; k < 8; ++k) acc[m][k] = 0.f;
#pragma unroll
    for (int m = 0; m < 5; ++m) {
      const float* hbase = sm.hb[m] + c + (r0 + 16 - R) * 32;
#pragma unroll
      for (int jj = 0; jj < 2 * R + 8; ++jj) {
        float v = hbase[jj * 32];
#pragma unroll
        for (int k = 0; k < 8; ++k) {
          if (k >= jj - 2 * R && k <= jj)
            acc[m][k] = fmaf(g[jj - k], v, acc[m][k]);
        }
      }
    }
#pragma unroll
    for (int k = 0; k < 8; ++k) {
      float mux = acc[0][k], muy = acc[1][k];
      float mxx = acc[2][k], myy = acc[3][k], mxy = acc[4][k];
      float mux2 = mux * mux, muy2 = muy * muy, muxy = mux * muy;
      float cs =
          (2.f * (mxy - muxy) + kC2) / ((mxx - mux2) + (myy - muy2) + kC2);
      Pcs[k] *= cs;
      if (LAST) {
        float lum = (2.f * muxy + kC1) / (mux2 + muy2 + kC1);
        lumP[k] = lum * Pcs[k];
      }
    }
  }

  // ---- L1 pass at last sigma: conv(|x-y|, g_sigma8), reusing hb[0] ----
  if (LAST) {
    __syncthreads();
    for (int idx = tid; idx < 64 * 8; idx += 256) {
      int pr = idx >> 3;
      int c0 = (idx & 7) << 2;
      float d[36];
      const float4* px = (const float4*)(sm.sx + pr * 64 + c0);
      const float4* py = (const float4*)(sm.sy + pr * 64 + c0);
#pragma unroll
      for (int q = 0; q < 9; ++q) {
        float4 vx = px[q], vy = py[q];
        d[4 * q + 0] = fabsf(vx.x - vy.x);
        d[4 * q + 1] = fabsf(vx.y - vy.y);
        d[4 * q + 2] = fabsf(vx.z - vy.z);
        d[4 * q + 3] = fabsf(vx.w - vy.w);
      }
#pragma unroll
      for (int o = 0; o < 4; ++o) {
        float a = 0.f;
#pragma unroll
        for (int j = 0; j < 33; ++j) a = fmaf(g[j], d[o + j], a);
        sm.hb[0][pr * 32 + c0 + o] = a;
      }
    }
    __syncthreads();
    if (tid < 128) {
      int c = tid & 31;
      int r0 = (tid >> 5) << 3;
      float a8[8];
#pragma unroll
      for (int k = 0; k < 8; ++k) a8[k] = 0.f;
      const float* hbase = sm.hb[0] + c + r0 * 32;
#pragma unroll
      for (int jj = 0; jj < 40; ++jj) {
        float v = hbase[jj * 32];
#pragma unroll
        for (int k = 0; k < 8; ++k) {
          if (k >= jj - 32 && k <= jj) a8[k] = fmaf(g[jj - k], v, a8[k]);
        }
      }
#pragma unroll
      for (int k = 0; k < 8; ++k) l1v[k] = a8[k];
    }
  }
}

__global__ __launch_bounds__(256, 2) void msssim_l1_kernel(
    const float* __restrict__ x, const float* __restrict__ y,
    const float* __restrict__ gm, float* __restrict__ out) {
  __shared__ Smem sm;
  const int tid = threadIdx.x;

  // 1D taps from the 2D mask center row: mask = outer(g,g)
  // g[j] = m[16][j] / sqrt(m[16][16])
  if (tid < 165) {
    int s = tid / 33;
    int j = tid - s * 33;
    float c = gm[s * 1089 + 16 * 33 + 16];
    sm.g1[tid] = gm[s * 1089 + 16 * 33 + j] * rsqrtf(c);
  }

  // load 64x64 halo patches (zero padding outside the image);
  // chunks are always fully in- or out-of-bounds (everything is 4-aligned)
  const float* xb = x + blockIdx.z * (512 * 512);
  const float* yb = y + blockIdx.z * (512 * 512);
  const int rb = blockIdx.y * 32 - 16;
  const int cb = blockIdx.x * 32 - 16;
  for (int f = tid; f < 1024; f += 256) {
    int pr = f >> 4;
    int pc = (f & 15) << 2;
    int gr = rb + pr, gc = cb + pc;
    float4 vx = make_float4(0.f, 0.f, 0.f, 0.f);
    float4 vy = vx;
    if (gr >= 0 && gr < 512 && gc >= 0 && gc < 512) {
      vx = *(const float4*)(xb + gr * 512 + gc);
      vy = *(const float4*)(yb + gr * 512 + gc);
    }
    *(float4*)(sm.sx + pr * 64 + pc) = vx;
    *(float4*)(sm.sy + pr * 64 + pc) = vy;
  }

  float Pcs[8], lumP[8], l1v[8];
#pragma unroll
  for (int k = 0; k < 8; ++k) {
    Pcs[k] = 1.f;
    lumP[k] = 0.f;
    l1v[k] = 0.f;
  }
  __syncthreads();

  // truncated radii: tails < e^-12 relative, negligible vs 0.137 abs threshold
  process_sigma<3, false>(sm, 0, tid, Pcs, lumP, l1v);
  process_sigma<5, false>(sm, 1, tid, Pcs, lumP, l1v);
  process_sigma<10, false>(sm, 2, tid, Pcs, lumP, l1v);
  process_sigma<16, false>(sm, 3, tid, Pcs, lumP, l1v);
  process_sigma<16, true>(sm, 4, tid, Pcs, lumP, l1v);

  // loss_mix = alpha*(1 - lum*PIcs) + (1-alpha)*gaussian_l1 ; out = 20*mean
  float lsum = 0.f;
  if (tid < 128) {
#pragma unroll
    for (int k = 0; k < 8; ++k)
      lsum += kAlpha * (1.f - lumP[k]) + (1.f - kAlpha) * l1v[k];
  }
#pragma unroll
  for (int off = 32; off > 0; off >>= 1) lsum += __shfl_down(lsum, off, 64);
  if ((tid & 63) == 0) sm.red[tid >> 6] = lsum;
  __syncthreads();
  if (tid == 0) {
    float t = sm.red[0] + sm.red[1] + sm.red[2] + sm.red[3];
    atomicAdd(out, t * (20.f / (16.f * 512.f * 512.f)));
  }
}

}  // namespace

extern "C" void kernel_launch(void* const* d_in, const int* in_sizes, int n_in,
                              void* d_out, int out_size, void* d_ws,
                              size_t ws_size, hipStream_t stream) {
  (void)in_sizes;
  (void)n_in;
  (void)d_ws;
  (void)ws_size;
  (void)out_size;
  const float* x = (const float*)d_in[0];
  const float* y = (const float*)d_in[1];
  const float* gm = (const float*)d_in[2];
  float* out = (float*)d_out;
  // d_out is poisoned before every timed launch; zero it for the atomic sum
  hipMemsetAsync(out, 0, sizeof(float), stream);
  dim3 grid(16, 16, 16);
  msssim_l1_kernel<<<grid, dim3(256), 0, stream>>>(x, y, gm, out);
}

// Round 2
// 326.032 us; speedup vs baseline: 1.5658x; 1.5658x over previous
//
#include <hip/hip_runtime.h>

namespace {

constexpr float kAlpha = 0.025f;
constexpr float kC1 = 1.0e-4f;  // (0.01*1)^2
constexpr float kC2 = 9.0e-4f;  // (0.03*1)^2

constexpr int SXS = 65;  // sx/sy row stride (pad 64->65: streamed reads <=2-way)
constexpr int HBS = 32;  // hb row stride (col-major-friendly vertical reads)

// LDS: 2*64*65*4 = 33.3 KB patches + 4*64*32*4 = 32 KB hb + taps = ~66 KB
// -> 2 blocks/CU
struct Smem {
  float sx[64 * SXS];
  float sy[64 * SXS];
  float hb[4][64 * HBS];  // maps: 0=x, 1=y, 2=x^2+y^2, 3=xy
  float g1[5 * 33];
  float red[4];
};

__device__ __forceinline__ float rfl(float v) {
  return __uint_as_float(__builtin_amdgcn_readfirstlane(__float_as_uint(v)));
}

// One sigma. H-pass: streaming row conv, 4 output cols/thread, 4 maps.
// V-pass: 128 threads, col-per-thread, 8-row strips, streaming col conv.
template <int R, bool LAST>
__device__ __forceinline__ void process_sigma(Smem& sm, int s, int tid,
                                              float Pcs[8], float lumP[8],
                                              float l1v[8]) {
  constexpr int T = 2 * R + 1;
  float gs[T];  // uniform -> SGPRs
  {
    const float* gb = sm.g1 + s * 33 + (16 - R);
#pragma unroll
    for (int j = 0; j < T; ++j) gs[j] = rfl(gb[j]);
  }

  __syncthreads();  // prev sigma's vertical reads of hb done; g1 ready

  // ---- horizontal: rows [16-R, 48+R), 32 cols, streaming ----
  constexpr int ROWS = 32 + 2 * R;
  for (int idx = tid; idx < ROWS * 8; idx += 256) {
    const int pr = (16 - R) + (idx >> 3);
    const int c0 = (idx & 7) << 2;
    const float* bx = sm.sx + pr * SXS + c0 + (16 - R);
    const float* by = sm.sy + pr * SXS + c0 + (16 - R);
    float ax[4] = {0.f, 0.f, 0.f, 0.f};
    float ay[4] = {0.f, 0.f, 0.f, 0.f};
    float a2[4] = {0.f, 0.f, 0.f, 0.f};
    float axy[4] = {0.f, 0.f, 0.f, 0.f};
#pragma unroll
    for (int jj = 0; jj < T + 3; ++jj) {
      float vx = bx[jj], vy = by[jj];
      float sq = fmaf(vy, vy, vx * vx);
      float pxy = vx * vy;
#pragma unroll
      for (int o = 0; o < 4; ++o) {
        if (o <= jj && jj - o < T) {  // compile-time predicate
          float g = gs[jj - o];
          ax[o] = fmaf(g, vx, ax[o]);
          ay[o] = fmaf(g, vy, ay[o]);
          a2[o] = fmaf(g, sq, a2[o]);
          axy[o] = fmaf(g, pxy, axy[o]);
        }
      }
    }
    const int off = pr * HBS + c0;  // 16B-aligned (c0 % 4 == 0, HBS = 32)
    *(float4*)(sm.hb[0] + off) = make_float4(ax[0], ax[1], ax[2], ax[3]);
    *(float4*)(sm.hb[1] + off) = make_float4(ay[0], ay[1], ay[2], ay[3]);
    *(float4*)(sm.hb[2] + off) = make_float4(a2[0], a2[1], a2[2], a2[3]);
    *(float4*)(sm.hb[3] + off) = make_float4(axy[0], axy[1], axy[2], axy[3]);
  }
  __syncthreads();

  // ---- vertical + combine (tid < 128); d=|x-y| precompute overlaps (LAST) --
  if (tid < 128) {
    const int c = tid & 31;
    const int r0 = (tid >> 5) << 3;
    float acc[4][8];
#pragma unroll
    for (int m = 0; m < 4; ++m)
#pragma unroll
      for (int k = 0; k < 8; ++k) acc[m][k] = 0.f;
#pragma unroll
    for (int m = 0; m < 4; ++m) {
      const float* hbase = sm.hb[m] + (16 - R + r0) * HBS + c;
#pragma unroll
      for (int jj = 0; jj < 2 * R + 8; ++jj) {
        float v = hbase[jj * HBS];
#pragma unroll
        for (int k = 0; k < 8; ++k) {
          if (k <= jj && jj - k <= 2 * R)
            acc[m][k] = fmaf(gs[jj - k], v, acc[m][k]);
        }
      }
    }
#pragma unroll
    for (int k = 0; k < 8; ++k) {
      float mux = acc[0][k], muy = acc[1][k];
      float m2 = acc[2][k], mxy = acc[3][k];
      float mux2 = mux * mux, muy2 = muy * muy, muxy = mux * muy;
      float cs = (2.f * (mxy - muxy) + kC2) / ((m2 - mux2 - muy2) + kC2);
      Pcs[k] *= cs;
      if (LAST)
        lumP[k] = ((2.f * muxy + kC1) / (mux2 + muy2 + kC1)) * Pcs[k];
    }
  } else if (LAST) {
    // threads 128..255: d = |x - y| into sy (H-pass reads of sy are done)
    for (int i = tid - 128; i < 4096; i += 128) {
      int a = (i >> 6) * SXS + (i & 63);
      sm.sy[a] = fabsf(sm.sx[a] - sm.sy[a]);
    }
  }

  // ---- L1 pass: conv(|x-y|, g_sigma8) ----
  if (LAST) {
    __syncthreads();  // V reads of hb done; d ready
    for (int idx = tid; idx < 64 * 8; idx += 256) {
      const int pr = idx >> 3;
      const int c0 = (idx & 7) << 2;
      const float* bd = sm.sy + pr * SXS + c0;
      float al[4] = {0.f, 0.f, 0.f, 0.f};
#pragma unroll
      for (int jj = 0; jj < 36; ++jj) {
        float v = bd[jj];
#pragma unroll
        for (int o = 0; o < 4; ++o) {
          if (o <= jj && jj - o < 33) al[o] = fmaf(gs[jj - o], v, al[o]);
        }
      }
      *(float4*)(sm.hb[0] + pr * HBS + c0) =
          make_float4(al[0], al[1], al[2], al[3]);
    }
    __syncthreads();
    if (tid < 128) {
      const int c = tid & 31;
      const int r0 = (tid >> 5) << 3;
      float a8[8];
#pragma unroll
      for (int k = 0; k < 8; ++k) a8[k] = 0.f;
      const float* hbase = sm.hb[0] + r0 * HBS + c;
#pragma unroll
      for (int jj = 0; jj < 40; ++jj) {
        float v = hbase[jj * HBS];
#pragma unroll
        for (int k = 0; k < 8; ++k) {
          if (k <= jj && jj - k <= 32) a8[k] = fmaf(gs[jj - k], v, a8[k]);
        }
      }
#pragma unroll
      for (int k = 0; k < 8; ++k) l1v[k] = a8[k];
    }
  }
}

__global__ __launch_bounds__(256, 2) void msssim_l1_kernel(
    const float* __restrict__ x, const float* __restrict__ y,
    const float* __restrict__ gm, float* __restrict__ out) {
  __shared__ Smem sm;
  const int tid = threadIdx.x;

  // 1D taps: mask = outer(g,g) -> g[j] = m[16][j] / sqrt(m[16][16])
  if (tid < 165) {
    int s = tid / 33;
    int j = tid - s * 33;
    float c = gm[s * 1089 + 16 * 33 + 16];
    sm.g1[tid] = gm[s * 1089 + 16 * 33 + j] * rsqrtf(c);
  }

  // 64x64 halo patches, zero-padded; scalar LDS stores (row stride 65)
  const float* xb = x + blockIdx.z * (512 * 512);
  const float* yb = y + blockIdx.z * (512 * 512);
  const int rb = blockIdx.y * 32 - 16;
  const int cb = blockIdx.x * 32 - 16;
  for (int f = tid; f < 1024; f += 256) {
    int pr = f >> 4;
    int pc = (f & 15) << 2;
    int gr = rb + pr, gc = cb + pc;
    float4 vx = make_float4(0.f, 0.f, 0.f, 0.f);
    float4 vy = vx;
    if (gr >= 0 && gr < 512 && gc >= 0 && gc < 512) {
      vx = *(const float4*)(xb + gr * 512 + gc);
      vy = *(const float4*)(yb + gr * 512 + gc);
    }
    int a = pr * SXS + pc;
    sm.sx[a + 0] = vx.x; sm.sx[a + 1] = vx.y;
    sm.sx[a + 2] = vx.z; sm.sx[a + 3] = vx.w;
    sm.sy[a + 0] = vy.x; sm.sy[a + 1] = vy.y;
    sm.sy[a + 2] = vy.z; sm.sy[a + 3] = vy.w;
  }

  float Pcs[8], lumP[8], l1v[8];
#pragma unroll
  for (int k = 0; k < 8; ++k) {
    Pcs[k] = 1.f;
    lumP[k] = 0.f;
    l1v[k] = 0.f;
  }

  // truncated radii: tails < e^-12 relative, negligible vs 0.137 threshold
  process_sigma<3, false>(sm, 0, tid, Pcs, lumP, l1v);
  process_sigma<5, false>(sm, 1, tid, Pcs, lumP, l1v);
  process_sigma<10, false>(sm, 2, tid, Pcs, lumP, l1v);
  process_sigma<16, false>(sm, 3, tid, Pcs, lumP, l1v);
  process_sigma<16, true>(sm, 4, tid, Pcs, lumP, l1v);

  // loss_mix = alpha*(1 - lum*PIcs) + (1-alpha)*gaussian_l1 ; out = 20*mean
  float lsum = 0.f;
  if (tid < 128) {
#pragma unroll
    for (int k = 0; k < 8; ++k)
      lsum += kAlpha * (1.f - lumP[k]) + (1.f - kAlpha) * l1v[k];
  }
#pragma unroll
  for (int off = 32; off > 0; off >>= 1) lsum += __shfl_down(lsum, off, 64);
  if ((tid & 63) == 0) sm.red[tid >> 6] = lsum;
  __syncthreads();
  if (tid == 0) {
    float t = sm.red[0] + sm.red[1] + sm.red[2] + sm.red[3];
    atomicAdd(out, t * (20.f / (16.f * 512.f * 512.f)));
  }
}

}  // namespace

extern "C" void kernel_launch(void* const* d_in, const int* in_sizes, int n_in,
                              void* d_out, int out_size, void* d_ws,
                              size_t ws_size, hipStream_t stream) {
  (void)in_sizes;
  (void)n_in;
  (void)d_ws;
  (void)ws_size;
  (void)out_size;
  const float* x = (const float*)d_in[0];
  const float* y = (const float*)d_in[1];
  const float* gm = (const float*)d_in[2];
  float* out = (float*)d_out;
  hipMemsetAsync(out, 0, sizeof(float), stream);
  dim3 grid(16, 16, 16);
  msssim_l1_kernel<<<grid, dim3(256), 0, stream>>>(x, y, gm, out);
}